// Round 20
// baseline (391.305 us; speedup 1.0000x reference)
//
#include <hip/hip_runtime.h>
#include <stdint.h>

typedef short short8 __attribute__((ext_vector_type(8)));
typedef float floatx4 __attribute__((ext_vector_type(4)));
typedef float floatx16 __attribute__((ext_vector_type(16)));

#define M_TOK 8192
#define K_IN  4096
#define N_OUT 4096
#define NTT   (K_IN / 32)    // 128 K-tiles of 32

// ---------- bf16 helpers (manual, RNE) ----------
static __device__ __forceinline__ float bf2f(ushort u) {
    union { uint32_t u; float f; } v;
    v.u = ((uint32_t)u) << 16;
    return v.f;
}
static __device__ __forceinline__ ushort f2bf(float f) {
    union { float f; uint32_t u; } v;
    v.f = f;
    uint32_t u = v.u;
    uint32_t r = (u + 0x7FFFu + ((u >> 16) & 1u)) >> 16;
    return (ushort)r;
}

// ---------- mask width detect: 2:4 invariant on rows 0-3, all 4096 columns ----------
__global__ __launch_bounds__(256) void detect_kernel(
    const unsigned char* __restrict__ mb, int* __restrict__ flags) {
    const ushort* mh = (const ushort*)mb;
    const unsigned int* mw = (const unsigned int*)mb;
    __shared__ int v[3];
    if (threadIdx.x < 3) v[threadIdx.x] = 0;
    __syncthreads();
    int l0 = 0, l1 = 0, l2 = 0;
    for (int o = threadIdx.x; o < 4096; o += 256) {
        int c1 = 0, c2 = 0, c4 = 0;
        #pragma unroll
        for (int r = 0; r < 4; ++r) {
            int idx = r * N_OUT + o;
            c1 += (mb[idx] != 0);
            c2 += (mh[idx] != 0);
            c4 += (mw[idx] != 0);
        }
        l0 += (c1 != 2); l1 += (c2 != 2); l2 += (c4 != 2);
    }
    atomicAdd(&v[0], l0); atomicAdd(&v[1], l1); atomicAdd(&v[2], l2);
    __syncthreads();
    if (threadIdx.x == 0) {
        int size = 4, best = v[2];
        if (v[1] < best) { size = 2; best = v[1]; }
        if (v[0] < best) { size = 1; }
        flags[0] = size;
    }
}

// ---------- fused prep: convert x (blocks 0..4095) + dequant (blocks 4096..8191) ----------
__global__ __launch_bounds__(256) void prep_kernel(
    const float* __restrict__ xf, ushort* __restrict__ Xb,
    const int* __restrict__ q, const void* __restrict__ maskp,
    const float* __restrict__ scales, ushort* __restrict__ Bt,
    const int* __restrict__ flagp) {
    const int tid = threadIdx.x;
    if (blockIdx.x < 4096) {
        const int total = M_TOK * K_IN;
        const int stride = 4096 * 256 * 8;
        for (int i = (blockIdx.x * 256 + tid) * 8; i < total; i += stride) {
            floatx4 f0 = *(const floatx4*)&xf[i];
            floatx4 f1 = *(const floatx4*)&xf[i + 4];
            short8 v;
            #pragma unroll
            for (int j = 0; j < 4; ++j) v[j]     = (short)f2bf(f0[j]);
            #pragma unroll
            for (int j = 0; j < 4; ++j) v[4 + j] = (short)f2bf(f1[j]);
            *(short8*)&Xb[i] = v;
        }
    } else {
        const int d  = blockIdx.x - 4096;
        const int i0 = (d & 63) * 64;        // in_f
        const int o0 = (d >> 6) * 64;        // out_f
        const int msize = flagp[0];
        const unsigned char* mb = (const unsigned char*)maskp;
        const ushort* mh = (const ushort*)maskp;
        const unsigned int* mi = (const unsigned int*)maskp;
        __shared__ ushort T[64][72];
        for (int p = 0; p < 16; ++p) {
            int idx = p * 256 + tid;
            int r = idx >> 6, c = idx & 63;
            size_t gi = (size_t)(i0 + r) * N_OUT + (o0 + c);
            bool m;
            if (msize == 1)      m = (mb[gi] != 0);
            else if (msize == 2) m = (mh[gi] != 0);
            else                 m = (mi[gi] != 0);
            float s = scales[o0 + c];
            float w = m ? (float)(q[gi] - 8) * s : 0.0f;
            T[r][c] = f2bf(w);
        }
        __syncthreads();
        for (int p = 0; p < 2; ++p) {
            int ol = p * 32 + (tid >> 3);
            int i8 = (tid & 7) * 8;
            short8 v;
            #pragma unroll
            for (int j = 0; j < 8; ++j) v[j] = (short)T[i8 + j][ol];
            *(short8*)&Bt[(size_t)(o0 + ol) * K_IN + i0 + i8] = v;
        }
    }
}

// ---------- bf16 GEMM: 128x256, 4 waves, BK=32, dbuf, 2 blocks/CU, 32x32x16 core ----------
// v20 = v17 (best schedule: 2 blocks/CU, dbuf, vmcnt(0) gates) with the MFMA
// core switched to 32x32x16. Pipe arithmetic (per CU, whole kernel):
//   16x16 core: LDS reads 295Kcyc (123us) + MFMA 318Kcyc (132us) ~ measured
//   275us plateau (serialized sum). The MIX is the binding constraint:
//   1 b128-read per 2.67 MFMA16. 32x32x16 gives 2x FLOP per read ->
//   reads 62us, MFMA 110us (m119 rate).
// v13's null doesn't apply: it ran 1-block/CU lockstep with a broken swizzle
// (2.5e7 conflicts). Here: same LDS layout/staging as v17 (chunk c^((r>>1)&3),
// 0-conflict proven); READ chunk (2ks+hi)^((r32>>1)&3), r32=lane&31,
// hi=lane>>5. Bank audit: quad = 4*(r32&1) + chunk; per (parity,chunk) pair
// exactly 8 lanes -> conflict-free floor.
// C/D (m74/m101, validated in v13's pass): col=lane&31,
// row=(reg&3)+8*(reg>>2)+4*hi.
#define GL2L16(gp, lbase)                                                      \
    __builtin_amdgcn_global_load_lds(                                          \
        (const __attribute__((address_space(1))) void*)(gp),                   \
        (__attribute__((address_space(3))) void*)(lbase), 16, 0, 0)

#define MFMA32(a, b, c) __builtin_amdgcn_mfma_f32_32x32x16_bf16(a, b, c, 0, 0, 0)

__global__ __launch_bounds__(256, 2) void gemm_kernel(
    const ushort* __restrict__ X,   // [M_TOK][K_IN] bf16 bits (workspace)
    const ushort* __restrict__ Bt,  // [N_OUT][K_IN] bf16 bits (workspace)
    float* __restrict__ Y) {        // [M_TOK][N_OUT] float32
    __shared__ ushort As[2][128][32];   // 16 KiB
    __shared__ ushort Bs[2][256][32];   // 32 KiB

    const int tid  = threadIdx.x;
    const int w    = tid >> 6;          // 0..3 (wave = N-column)
    const int lane = tid & 63;

    // locality mapping (bijective over 1024 blocks): per-XCD M/N regions
    const int xcd = blockIdx.x & 7;
    const int jj  = (blockIdx.x >> 3) & 63;
    const int rr0 = blockIdx.x >> 9;            // 0..1
    const int m_tile = rr0 * 32 + (xcd & 1) * 16 + (jj & 15);  // 0..63
    const int n_tile = (xcd >> 1) * 4 + (jj >> 4);             // 0..15
    const int row0 = m_tile * 128;
    const int col0 = n_tile * 256;

    floatx16 acc[4][2] = {};

    // staging (unchanged, 0-conflict): 4 lanes/row; chunk G=(tid&3)^((tid>>3)&3)
    const int schunk = (tid & 3) ^ ((tid >> 3) & 3);
    const ushort* gA = X  + (size_t)(row0 + (tid >> 2)) * K_IN + schunk * 8;
    const ushort* gB = Bt + (size_t)(col0 + (tid >> 2)) * K_IN + schunk * 8;

    const int r32 = lane & 31, hi = lane >> 5;
    const int fsw = (r32 >> 1) & 3;

    // stage tile tt into buffer BF: A 2 loads, B 4 loads per thread
    #define STG(BF, tt)                                                        \
        do {                                                                   \
            GL2L16(gA + (size_t)(tt) * 32,                                     \
                   (char*)&As[BF][w * 16][0] + lane * 16);                     \
            GL2L16(gA + (size_t)64 * K_IN + (size_t)(tt) * 32,                 \
                   (char*)&As[BF][64 + w * 16][0] + lane * 16);                \
            GL2L16(gB + (size_t)(tt) * 32,                                     \
                   (char*)&Bs[BF][w * 16][0] + lane * 16);                     \
            GL2L16(gB + (size_t)64 * K_IN + (size_t)(tt) * 32,                 \
                   (char*)&Bs[BF][64 + w * 16][0] + lane * 16);                \
            GL2L16(gB + (size_t)128 * K_IN + (size_t)(tt) * 32,                \
                   (char*)&Bs[BF][128 + w * 16][0] + lane * 16);               \
            GL2L16(gB + (size_t)192 * K_IN + (size_t)(tt) * 32,                \
                   (char*)&Bs[BF][192 + w * 16][0] + lane * 16);               \
        } while (0)

    // one K-tile: 12 frag reads || stage next ; bar ; lgkm ; 16 MFMA32 ; gate ; bar
    #define TILE(BF, T)                                                        \
        do {                                                                   \
            short8 a0[4], a1[4], b0[2], b1[2];                                 \
            _Pragma("unroll")                                                  \
            for (int nb = 0; nb < 2; ++nb) {                                   \
                b0[nb] = *(const short8*)&Bs[BF][w * 64 + nb * 32 + r32]       \
                             [((0 + hi) ^ fsw) * 8];                           \
                b1[nb] = *(const short8*)&Bs[BF][w * 64 + nb * 32 + r32]       \
                             [((2 + hi) ^ fsw) * 8];                           \
            }                                                                  \
            _Pragma("unroll")                                                  \
            for (int mb = 0; mb < 4; ++mb) {                                   \
                a0[mb] = *(const short8*)&As[BF][mb * 32 + r32]                \
                             [((0 + hi) ^ fsw) * 8];                           \
                a1[mb] = *(const short8*)&As[BF][mb * 32 + r32]                \
                             [((2 + hi) ^ fsw) * 8];                           \
            }                                                                  \
            if ((T) + 1 < NTT) STG((BF) ^ 1, (T) + 1);                         \
            __builtin_amdgcn_s_barrier();                                      \
            asm volatile("s_waitcnt lgkmcnt(0)" ::: "memory");                 \
            __builtin_amdgcn_sched_barrier(0);                                 \
            __builtin_amdgcn_s_setprio(1);                                     \
            _Pragma("unroll")                                                  \
            for (int mb = 0; mb < 4; ++mb)                                     \
                _Pragma("unroll")                                              \
                for (int nb = 0; nb < 2; ++nb)                                 \
                    acc[mb][nb] = MFMA32(a0[mb], b0[nb], acc[mb][nb]);         \
            _Pragma("unroll")                                                  \
            for (int mb = 0; mb < 4; ++mb)                                     \
                _Pragma("unroll")                                              \
                for (int nb = 0; nb < 2; ++nb)                                 \
                    acc[mb][nb] = MFMA32(a1[mb], b1[nb], acc[mb][nb]);         \
            __builtin_amdgcn_s_setprio(0);                                     \
            asm volatile("s_waitcnt vmcnt(0)" ::: "memory");                   \
            __builtin_amdgcn_s_barrier();                                      \
        } while (0)

    // prologue: tile 0 -> buf0
    STG(0, 0);
    asm volatile("s_waitcnt vmcnt(0)" ::: "memory");
    __builtin_amdgcn_s_barrier();

    for (int t = 0; t < NTT; t += 2) {
        TILE(0, t);
        TILE(1, t + 1);
    }

    // epilogue: 32x32 C/D layout col=lane&31, row=(reg&3)+8*(reg>>2)+4*hi
    #pragma unroll
    for (int mb = 0; mb < 4; ++mb)
        #pragma unroll
        for (int nb = 0; nb < 2; ++nb)
            #pragma unroll
            for (int reg = 0; reg < 16; ++reg) {
                int crow = (reg & 3) + 8 * (reg >> 2) + 4 * hi;
                int rr = row0 + mb * 32 + crow;
                int cc = col0 + w * 64 + nb * 32 + r32;
                Y[(size_t)rr * N_OUT + cc] = acc[mb][nb][reg];
            }
    #undef TILE
    #undef STG
}

// ---------- slow correct fallback (only if ws too small) ----------
__global__ __launch_bounds__(256) void fallback_kernel(
    const float* __restrict__ xf, const int* __restrict__ q,
    const void* __restrict__ maskp, const float* __restrict__ scales,
    float* __restrict__ Y, const int* __restrict__ flagp) {
    const int msize = flagp[0];
    const int o = blockIdx.x * 256 + threadIdx.x;
    const int t = blockIdx.y;
    const unsigned char* mb = (const unsigned char*)maskp;
    const ushort* mh = (const ushort*)maskp;
    const unsigned int* mi = (const unsigned int*)maskp;
    float s = scales[o];
    float acc = 0.f;
    for (int i = 0; i < K_IN; ++i) {
        float x = bf2f(f2bf(xf[(size_t)t * K_IN + i]));
        size_t gi = (size_t)i * N_OUT + o;
        bool m;
        if (msize == 1)      m = (mb[gi] != 0);
        else if (msize == 2) m = (mh[gi] != 0);
        else                 m = (mi[gi] != 0);
        if (m) acc += x * bf2f(f2bf((float)(q[gi] - 8) * s));
    }
    Y[(size_t)t * N_OUT + o] = acc;
}

extern "C" void kernel_launch(void* const* d_in, const int* in_sizes, int n_in,
                              void* d_out, int out_size, void* d_ws, size_t ws_size,
                              hipStream_t stream) {
    const float* x      = (const float*)d_in[0];
    const int*   q      = (const int*)d_in[1];
    const void*  mask   = d_in[2];
    const float* scales = (const float*)d_in[3];
    float* y = (float*)d_out;

    const size_t BT_OFF = 64;
    const size_t XB_OFF = BT_OFF + (size_t)N_OUT * K_IN * 2;   // 64 + 32MB
    const size_t need   = XB_OFF + (size_t)M_TOK * K_IN * 2;   // + 64MB

    int* flags = (int*)d_ws;
    detect_kernel<<<1, 256, 0, stream>>>((const unsigned char*)mask, flags);

    if (ws_size >= need) {
        ushort* Bt = (ushort*)((char*)d_ws + BT_OFF);
        ushort* Xb = (ushort*)((char*)d_ws + XB_OFF);
        prep_kernel<<<8192, 256, 0, stream>>>(x, Xb, q, mask, scales, Bt, flags);
        gemm_kernel<<<dim3((M_TOK / 128) * (N_OUT / 256)), 256, 0, stream>>>(
            Xb, Bt, y);
    } else {
        fallback_kernel<<<dim3(N_OUT / 256, M_TOK), 256, 0, stream>>>(
            x, q, mask, scales, y, flags);
    }
}

// Round 21
// 389.448 us; speedup vs baseline: 1.0048x; 1.0048x over previous
//
#include <hip/hip_runtime.h>
#include <stdint.h>

typedef short short8 __attribute__((ext_vector_type(8)));
typedef float floatx4 __attribute__((ext_vector_type(4)));
typedef float floatx16 __attribute__((ext_vector_type(16)));

#define M_TOK 8192
#define K_IN  4096
#define N_OUT 4096
#define NTT   (K_IN / 32)    // 128 K-tiles of 32

// ---------- bf16 helpers (manual, RNE) ----------
static __device__ __forceinline__ float bf2f(ushort u) {
    union { uint32_t u; float f; } v;
    v.u = ((uint32_t)u) << 16;
    return v.f;
}
static __device__ __forceinline__ ushort f2bf(float f) {
    union { float f; uint32_t u; } v;
    v.f = f;
    uint32_t u = v.u;
    uint32_t r = (u + 0x7FFFu + ((u >> 16) & 1u)) >> 16;
    return (ushort)r;
}

// ---------- mask width detect: 2:4 invariant on rows 0-3, all 4096 columns ----------
__global__ __launch_bounds__(256) void detect_kernel(
    const unsigned char* __restrict__ mb, int* __restrict__ flags) {
    const ushort* mh = (const ushort*)mb;
    const unsigned int* mw = (const unsigned int*)mb;
    __shared__ int v[3];
    if (threadIdx.x < 3) v[threadIdx.x] = 0;
    __syncthreads();
    int l0 = 0, l1 = 0, l2 = 0;
    for (int o = threadIdx.x; o < 4096; o += 256) {
        int c1 = 0, c2 = 0, c4 = 0;
        #pragma unroll
        for (int r = 0; r < 4; ++r) {
            int idx = r * N_OUT + o;
            c1 += (mb[idx] != 0);
            c2 += (mh[idx] != 0);
            c4 += (mw[idx] != 0);
        }
        l0 += (c1 != 2); l1 += (c2 != 2); l2 += (c4 != 2);
    }
    atomicAdd(&v[0], l0); atomicAdd(&v[1], l1); atomicAdd(&v[2], l2);
    __syncthreads();
    if (threadIdx.x == 0) {
        int size = 4, best = v[2];
        if (v[1] < best) { size = 2; best = v[1]; }
        if (v[0] < best) { size = 1; }
        flags[0] = size;
    }
}

// ---------- fused prep: convert x (blocks 0..4095) + dequant (blocks 4096..8191) ----------
__global__ __launch_bounds__(256) void prep_kernel(
    const float* __restrict__ xf, ushort* __restrict__ Xb,
    const int* __restrict__ q, const void* __restrict__ maskp,
    const float* __restrict__ scales, ushort* __restrict__ Bt,
    const int* __restrict__ flagp) {
    const int tid = threadIdx.x;
    if (blockIdx.x < 4096) {
        const int total = M_TOK * K_IN;
        const int stride = 4096 * 256 * 8;
        for (int i = (blockIdx.x * 256 + tid) * 8; i < total; i += stride) {
            floatx4 f0 = *(const floatx4*)&xf[i];
            floatx4 f1 = *(const floatx4*)&xf[i + 4];
            short8 v;
            #pragma unroll
            for (int j = 0; j < 4; ++j) v[j]     = (short)f2bf(f0[j]);
            #pragma unroll
            for (int j = 0; j < 4; ++j) v[4 + j] = (short)f2bf(f1[j]);
            *(short8*)&Xb[i] = v;
        }
    } else {
        const int d  = blockIdx.x - 4096;
        const int i0 = (d & 63) * 64;        // in_f
        const int o0 = (d >> 6) * 64;        // out_f
        const int msize = flagp[0];
        const unsigned char* mb = (const unsigned char*)maskp;
        const ushort* mh = (const ushort*)maskp;
        const unsigned int* mi = (const unsigned int*)maskp;
        __shared__ ushort T[64][72];
        for (int p = 0; p < 16; ++p) {
            int idx = p * 256 + tid;
            int r = idx >> 6, c = idx & 63;
            size_t gi = (size_t)(i0 + r) * N_OUT + (o0 + c);
            bool m;
            if (msize == 1)      m = (mb[gi] != 0);
            else if (msize == 2) m = (mh[gi] != 0);
            else                 m = (mi[gi] != 0);
            float s = scales[o0 + c];
            float w = m ? (float)(q[gi] - 8) * s : 0.0f;
            T[r][c] = f2bf(w);
        }
        __syncthreads();
        for (int p = 0; p < 2; ++p) {
            int ol = p * 32 + (tid >> 3);
            int i8 = (tid & 7) * 8;
            short8 v;
            #pragma unroll
            for (int j = 0; j < 8; ++j) v[j] = (short)T[i8 + j][ol];
            *(short8*)&Bt[(size_t)(o0 + ol) * K_IN + i0 + i8] = v;
        }
    }
}

// ---------- bf16 GEMM: 128x256, 4 waves, BK=32, dbuf, 2 blocks/CU, 32x32x16 core ----------
// v21 = v20 with the CORRECT conflict-free swizzle for 32x32 fragment reads.
// Conflict algebra (4B banks): lanes sharing (row-parity, chunk) collide.
// The 8-lane class for 32x32 reads is {r32, r32+8, r32+16, r32+24} x {hi}.
// Old swz(r)=(r>>1)&3 is blind to bit 3 -> class spans only 2 chunks
// (4-way, 1.58x — the measured 2.5e7). New swz sees the octave:
//   swz(r) = ((r>>1)&3) ^ ((r>>3)&3)
// -> 4 octaves carry 4 distinct swz; chunk = ks^hi^swz covers all 4 chunks
// x 2 lanes = 2-way = free (m136).
// Write side (rule 21 both-sides): row = tid>>2 (+64/128/192: both terms
// invariant mod 4) -> source chunk G = (tid&3)^((tid>>3)&3)^((tid>>5)&3);
// global reads remain 64B-coalesced (per-4-lane chunk permutation).
// Read side: fsw = ((r32>>1)&3)^((r32>>3)&3) (mb*32, nb*32, w*64 vanish).
// Schedule/geometry = v17 (best: 274.5us): 2 blocks/CU, dbuf, vmcnt(0) gates.
#define GL2L16(gp, lbase)                                                      \
    __builtin_amdgcn_global_load_lds(                                          \
        (const __attribute__((address_space(1))) void*)(gp),                   \
        (__attribute__((address_space(3))) void*)(lbase), 16, 0, 0)

#define MFMA32(a, b, c) __builtin_amdgcn_mfma_f32_32x32x16_bf16(a, b, c, 0, 0, 0)

__global__ __launch_bounds__(256, 2) void gemm_kernel(
    const ushort* __restrict__ X,   // [M_TOK][K_IN] bf16 bits (workspace)
    const ushort* __restrict__ Bt,  // [N_OUT][K_IN] bf16 bits (workspace)
    float* __restrict__ Y) {        // [M_TOK][N_OUT] float32
    __shared__ ushort As[2][128][32];   // 16 KiB
    __shared__ ushort Bs[2][256][32];   // 32 KiB

    const int tid  = threadIdx.x;
    const int w    = tid >> 6;          // 0..3 (wave = N-column)
    const int lane = tid & 63;

    // locality mapping (bijective over 1024 blocks): per-XCD M/N regions
    const int xcd = blockIdx.x & 7;
    const int jj  = (blockIdx.x >> 3) & 63;
    const int rr0 = blockIdx.x >> 9;            // 0..1
    const int m_tile = rr0 * 32 + (xcd & 1) * 16 + (jj & 15);  // 0..63
    const int n_tile = (xcd >> 1) * 4 + (jj >> 4);             // 0..15
    const int row0 = m_tile * 128;
    const int col0 = n_tile * 256;

    floatx16 acc[4][2] = {};

    // staging: 4 lanes/row; row = tid>>2; source chunk = linear-chunk ^ swz(row)
    const int schunk = (tid & 3) ^ ((tid >> 3) & 3) ^ ((tid >> 5) & 3);
    const ushort* gA = X  + (size_t)(row0 + (tid >> 2)) * K_IN + schunk * 8;
    const ushort* gB = Bt + (size_t)(col0 + (tid >> 2)) * K_IN + schunk * 8;

    const int r32 = lane & 31, hi = lane >> 5;
    const int fsw = ((r32 >> 1) & 3) ^ ((r32 >> 3) & 3);

    // stage tile tt into buffer BF: A 2 loads, B 4 loads per thread
    #define STG(BF, tt)                                                        \
        do {                                                                   \
            GL2L16(gA + (size_t)(tt) * 32,                                     \
                   (char*)&As[BF][w * 16][0] + lane * 16);                     \
            GL2L16(gA + (size_t)64 * K_IN + (size_t)(tt) * 32,                 \
                   (char*)&As[BF][64 + w * 16][0] + lane * 16);                \
            GL2L16(gB + (size_t)(tt) * 32,                                     \
                   (char*)&Bs[BF][w * 16][0] + lane * 16);                     \
            GL2L16(gB + (size_t)64 * K_IN + (size_t)(tt) * 32,                 \
                   (char*)&Bs[BF][64 + w * 16][0] + lane * 16);                \
            GL2L16(gB + (size_t)128 * K_IN + (size_t)(tt) * 32,                \
                   (char*)&Bs[BF][128 + w * 16][0] + lane * 16);               \
            GL2L16(gB + (size_t)192 * K_IN + (size_t)(tt) * 32,                \
                   (char*)&Bs[BF][192 + w * 16][0] + lane * 16);               \
        } while (0)

    // one K-tile: 12 frag reads || stage next ; bar ; lgkm ; 16 MFMA32 ; gate ; bar
    #define TILE(BF, T)                                                        \
        do {                                                                   \
            short8 a0[4], a1[4], b0[2], b1[2];                                 \
            _Pragma("unroll")                                                  \
            for (int nb = 0; nb < 2; ++nb) {                                   \
                b0[nb] = *(const short8*)&Bs[BF][w * 64 + nb * 32 + r32]       \
                             [((0 + hi) ^ fsw) * 8];                           \
                b1[nb] = *(const short8*)&Bs[BF][w * 64 + nb * 32 + r32]       \
                             [((2 + hi) ^ fsw) * 8];                           \
            }                                                                  \
            _Pragma("unroll")                                                  \
            for (int mb = 0; mb < 4; ++mb) {                                   \
                a0[mb] = *(const short8*)&As[BF][mb * 32 + r32]                \
                             [((0 + hi) ^ fsw) * 8];                           \
                a1[mb] = *(const short8*)&As[BF][mb * 32 + r32]                \
                             [((2 + hi) ^ fsw) * 8];                           \
            }                                                                  \
            if ((T) + 1 < NTT) STG((BF) ^ 1, (T) + 1);                         \
            __builtin_amdgcn_s_barrier();                                      \
            asm volatile("s_waitcnt lgkmcnt(0)" ::: "memory");                 \
            __builtin_amdgcn_sched_barrier(0);                                 \
            __builtin_amdgcn_s_setprio(1);                                     \
            _Pragma("unroll")                                                  \
            for (int mb = 0; mb < 4; ++mb)                                     \
                _Pragma("unroll")                                              \
                for (int nb = 0; nb < 2; ++nb)                                 \
                    acc[mb][nb] = MFMA32(a0[mb], b0[nb], acc[mb][nb]);         \
            _Pragma("unroll")                                                  \
            for (int mb = 0; mb < 4; ++mb)                                     \
                _Pragma("unroll")                                              \
                for (int nb = 0; nb < 2; ++nb)                                 \
                    acc[mb][nb] = MFMA32(a1[mb], b1[nb], acc[mb][nb]);         \
            __builtin_amdgcn_s_setprio(0);                                     \
            asm volatile("s_waitcnt vmcnt(0)" ::: "memory");                   \
            __builtin_amdgcn_s_barrier();                                      \
        } while (0)

    // prologue: tile 0 -> buf0
    STG(0, 0);
    asm volatile("s_waitcnt vmcnt(0)" ::: "memory");
    __builtin_amdgcn_s_barrier();

    for (int t = 0; t < NTT; t += 2) {
        TILE(0, t);
        TILE(1, t + 1);
    }

    // epilogue: 32x32 C/D layout col=lane&31, row=(reg&3)+8*(reg>>2)+4*hi
    #pragma unroll
    for (int mb = 0; mb < 4; ++mb)
        #pragma unroll
        for (int nb = 0; nb < 2; ++nb)
            #pragma unroll
            for (int reg = 0; reg < 16; ++reg) {
                int crow = (reg & 3) + 8 * (reg >> 2) + 4 * hi;
                int rr = row0 + mb * 32 + crow;
                int cc = col0 + w * 64 + nb * 32 + r32;
                Y[(size_t)rr * N_OUT + cc] = acc[mb][nb][reg];
            }
    #undef TILE
    #undef STG
}

// ---------- slow correct fallback (only if ws too small) ----------
__global__ __launch_bounds__(256) void fallback_kernel(
    const float* __restrict__ xf, const int* __restrict__ q,
    const void* __restrict__ maskp, const float* __restrict__ scales,
    float* __restrict__ Y, const int* __restrict__ flagp) {
    const int msize = flagp[0];
    const int o = blockIdx.x * 256 + threadIdx.x;
    const int t = blockIdx.y;
    const unsigned char* mb = (const unsigned char*)maskp;
    const ushort* mh = (const ushort*)maskp;
    const unsigned int* mi = (const unsigned int*)maskp;
    float s = scales[o];
    float acc = 0.f;
    for (int i = 0; i < K_IN; ++i) {
        float x = bf2f(f2bf(xf[(size_t)t * K_IN + i]));
        size_t gi = (size_t)i * N_OUT + o;
        bool m;
        if (msize == 1)      m = (mb[gi] != 0);
        else if (msize == 2) m = (mh[gi] != 0);
        else                 m = (mi[gi] != 0);
        if (m) acc += x * bf2f(f2bf((float)(q[gi] - 8) * s));
    }
    Y[(size_t)t * N_OUT + o] = acc;
}

extern "C" void kernel_launch(void* const* d_in, const int* in_sizes, int n_in,
                              void* d_out, int out_size, void* d_ws, size_t ws_size,
                              hipStream_t stream) {
    const float* x      = (const float*)d_in[0];
    const int*   q      = (const int*)d_in[1];
    const void*  mask   = d_in[2];
    const float* scales = (const float*)d_in[3];
    float* y = (float*)d_out;

    const size_t BT_OFF = 64;
    const size_t XB_OFF = BT_OFF + (size_t)N_OUT * K_IN * 2;   // 64 + 32MB
    const size_t need   = XB_OFF + (size_t)M_TOK * K_IN * 2;   // + 64MB

    int* flags = (int*)d_ws;
    detect_kernel<<<1, 256, 0, stream>>>((const unsigned char*)mask, flags);

    if (ws_size >= need) {
        ushort* Bt = (ushort*)((char*)d_ws + BT_OFF);
        ushort* Xb = (ushort*)((char*)d_ws + XB_OFF);
        prep_kernel<<<8192, 256, 0, stream>>>(x, Xb, q, mask, scales, Bt, flags);
        gemm_kernel<<<dim3((M_TOK / 128) * (N_OUT / 256)), 256, 0, stream>>>(
            Xb, Bt, y);
    } else {
        fallback_kernel<<<dim3(N_OUT / 256, M_TOK), 256, 0, stream>>>(
            x, q, mask, scales, y, flags);
    }
}

// Round 22
// 360.153 us; speedup vs baseline: 1.0865x; 1.0813x over previous
//
#include <hip/hip_runtime.h>
#include <stdint.h>

typedef short short8 __attribute__((ext_vector_type(8)));
typedef float floatx4 __attribute__((ext_vector_type(4)));

#define M_TOK 8192
#define K_IN  4096
#define N_OUT 4096
#define NTT   (K_IN / 32)    // 128 K-tiles of 32

// ---------- bf16 helpers (manual, RNE) ----------
static __device__ __forceinline__ float bf2f(ushort u) {
    union { uint32_t u; float f; } v;
    v.u = ((uint32_t)u) << 16;
    return v.f;
}
static __device__ __forceinline__ ushort f2bf(float f) {
    union { float f; uint32_t u; } v;
    v.f = f;
    uint32_t u = v.u;
    uint32_t r = (u + 0x7FFFu + ((u >> 16) & 1u)) >> 16;
    return (ushort)r;
}

// ---------- mask width detect: 2:4 invariant on rows 0-3, all 4096 columns ----------
__global__ __launch_bounds__(256) void detect_kernel(
    const unsigned char* __restrict__ mb, int* __restrict__ flags) {
    const ushort* mh = (const ushort*)mb;
    const unsigned int* mw = (const unsigned int*)mb;
    __shared__ int v[3];
    if (threadIdx.x < 3) v[threadIdx.x] = 0;
    __syncthreads();
    int l0 = 0, l1 = 0, l2 = 0;
    for (int o = threadIdx.x; o < 4096; o += 256) {
        int c1 = 0, c2 = 0, c4 = 0;
        #pragma unroll
        for (int r = 0; r < 4; ++r) {
            int idx = r * N_OUT + o;
            c1 += (mb[idx] != 0);
            c2 += (mh[idx] != 0);
            c4 += (mw[idx] != 0);
        }
        l0 += (c1 != 2); l1 += (c2 != 2); l2 += (c4 != 2);
    }
    atomicAdd(&v[0], l0); atomicAdd(&v[1], l1); atomicAdd(&v[2], l2);
    __syncthreads();
    if (threadIdx.x == 0) {
        int size = 4, best = v[2];
        if (v[1] < best) { size = 2; best = v[1]; }
        if (v[0] < best) { size = 1; }
        flags[0] = size;
    }
}

// ---------- fused prep: convert x (blocks 0..4095) + dequant (blocks 4096..8191) ----------
__global__ __launch_bounds__(256) void prep_kernel(
    const float* __restrict__ xf, ushort* __restrict__ Xb,
    const int* __restrict__ q, const void* __restrict__ maskp,
    const float* __restrict__ scales, ushort* __restrict__ Bt,
    const int* __restrict__ flagp) {
    const int tid = threadIdx.x;
    if (blockIdx.x < 4096) {
        const int total = M_TOK * K_IN;
        const int stride = 4096 * 256 * 8;
        for (int i = (blockIdx.x * 256 + tid) * 8; i < total; i += stride) {
            floatx4 f0 = *(const floatx4*)&xf[i];
            floatx4 f1 = *(const floatx4*)&xf[i + 4];
            short8 v;
            #pragma unroll
            for (int j = 0; j < 4; ++j) v[j]     = (short)f2bf(f0[j]);
            #pragma unroll
            for (int j = 0; j < 4; ++j) v[4 + j] = (short)f2bf(f1[j]);
            *(short8*)&Xb[i] = v;
        }
    } else {
        const int d  = blockIdx.x - 4096;
        const int i0 = (d & 63) * 64;        // in_f
        const int o0 = (d >> 6) * 64;        // out_f
        const int msize = flagp[0];
        const unsigned char* mb = (const unsigned char*)maskp;
        const ushort* mh = (const ushort*)maskp;
        const unsigned int* mi = (const unsigned int*)maskp;
        __shared__ ushort T[64][72];
        for (int p = 0; p < 16; ++p) {
            int idx = p * 256 + tid;
            int r = idx >> 6, c = idx & 63;
            size_t gi = (size_t)(i0 + r) * N_OUT + (o0 + c);
            bool m;
            if (msize == 1)      m = (mb[gi] != 0);
            else if (msize == 2) m = (mh[gi] != 0);
            else                 m = (mi[gi] != 0);
            float s = scales[o0 + c];
            float w = m ? (float)(q[gi] - 8) * s : 0.0f;
            T[r][c] = f2bf(w);
        }
        __syncthreads();
        for (int p = 0; p < 2; ++p) {
            int ol = p * 32 + (tid >> 3);
            int i8 = (tid & 7) * 8;
            short8 v;
            #pragma unroll
            for (int j = 0; j < 8; ++j) v[j] = (short)T[i8 + j][ol];
            *(short8*)&Bt[(size_t)(o0 + ol) * K_IN + i0 + i8] = v;
        }
    }
}

// ---------- bf16 GEMM: 128x256, 4 waves, BK=32, dbuf, 2 blocks/CU + STAGGER ----------
// v22 = v17 exactly (best measured: 274.5us GEMM, 0 conflicts) + a half-tile
// stagger for odd blocks. Pipe audit (measured rates): per CU, LDS-pipe
// 123us + MFMA 134us; measured 274.5 = serialized SUM, true overlap = max
// ~160us. Hypothesis: the 2 resident blocks are PHASE-LOCKED (identical
// code + barrier cadence + near-identical HBM returns) so both hit their
// 12-read burst windows together (serializing on the CU-shared LDS pipe),
// then both do MFMA while LDS idles. One-time ~640cyc s_sleep for odd
// blocks de-phases them so one block's MFMA cluster covers the sibling's
// read burst. Single-variable change vs v17.
#define GL2L16(gp, lbase)                                                      \
    __builtin_amdgcn_global_load_lds(                                          \
        (const __attribute__((address_space(1))) void*)(gp),                   \
        (__attribute__((address_space(3))) void*)(lbase), 16, 0, 0)

#define MFMA16(a, b, c) __builtin_amdgcn_mfma_f32_16x16x32_bf16(a, b, c, 0, 0, 0)

__global__ __launch_bounds__(256, 2) void gemm_kernel(
    const ushort* __restrict__ X,   // [M_TOK][K_IN] bf16 bits (workspace)
    const ushort* __restrict__ Bt,  // [N_OUT][K_IN] bf16 bits (workspace)
    float* __restrict__ Y) {        // [M_TOK][N_OUT] float32
    __shared__ ushort As[2][128][32];   // 16 KiB
    __shared__ ushort Bs[2][256][32];   // 32 KiB

    const int tid  = threadIdx.x;
    const int w    = tid >> 6;          // 0..3 (wave = N-column)
    const int lane = tid & 63;

    // de-phase the sibling block on this CU (~640 cyc, one-time)
    if (blockIdx.x & 1) __builtin_amdgcn_s_sleep(10);

    // locality mapping (bijective over 1024 blocks): per-XCD M/N regions
    const int xcd = blockIdx.x & 7;
    const int jj  = (blockIdx.x >> 3) & 63;
    const int rr0 = blockIdx.x >> 9;            // 0..1
    const int m_tile = rr0 * 32 + (xcd & 1) * 16 + (jj & 15);  // 0..63
    const int n_tile = (xcd >> 1) * 4 + (jj >> 4);             // 0..15
    const int row0 = m_tile * 128;
    const int col0 = n_tile * 256;

    floatx4 acc[8][4] = {};

    // staging: 4 lanes/row; row = tid>>2 (+64*l); chunk G=(tid&3)^((tid>>3)&3)
    const int schunk = (tid & 3) ^ ((tid >> 3) & 3);
    const ushort* gA = X  + (size_t)(row0 + (tid >> 2)) * K_IN + schunk * 8;
    const ushort* gB = Bt + (size_t)(col0 + (tid >> 2)) * K_IN + schunk * 8;

    const int fr = lane & 15, g = lane >> 4;
    const int fsw = (fr >> 1) & 3;

    // stage tile tt into buffer BF: A 2 loads, B 4 loads per thread
    #define STG(BF, tt)                                                        \
        do {                                                                   \
            GL2L16(gA + (size_t)(tt) * 32,                                     \
                   (char*)&As[BF][w * 16][0] + lane * 16);                     \
            GL2L16(gA + (size_t)64 * K_IN + (size_t)(tt) * 32,                 \
                   (char*)&As[BF][64 + w * 16][0] + lane * 16);                \
            GL2L16(gB + (size_t)(tt) * 32,                                     \
                   (char*)&Bs[BF][w * 16][0] + lane * 16);                     \
            GL2L16(gB + (size_t)64 * K_IN + (size_t)(tt) * 32,                 \
                   (char*)&Bs[BF][64 + w * 16][0] + lane * 16);                \
            GL2L16(gB + (size_t)128 * K_IN + (size_t)(tt) * 32,                \
                   (char*)&Bs[BF][128 + w * 16][0] + lane * 16);               \
            GL2L16(gB + (size_t)192 * K_IN + (size_t)(tt) * 32,                \
                   (char*)&Bs[BF][192 + w * 16][0] + lane * 16);               \
        } while (0)

    // one K-tile: 12 frag reads || stage next ; bar ; lgkm ; 32 MFMA ; gate ; bar
    #define TILE(BF, T)                                                        \
        do {                                                                   \
            short8 afr[8], bfr[4];                                             \
            _Pragma("unroll")                                                  \
            for (int n = 0; n < 4; ++n)                                        \
                bfr[n] = *(const short8*)&Bs[BF][w * 64 + n * 16 + fr]         \
                             [(g ^ fsw) * 8];                                  \
            _Pragma("unroll")                                                  \
            for (int m = 0; m < 8; ++m)                                        \
                afr[m] = *(const short8*)&As[BF][m * 16 + fr][(g ^ fsw) * 8];  \
            if ((T) + 1 < NTT) STG((BF) ^ 1, (T) + 1);                         \
            __builtin_amdgcn_s_barrier();                                      \
            asm volatile("s_waitcnt lgkmcnt(0)" ::: "memory");                 \
            __builtin_amdgcn_sched_barrier(0);                                 \
            __builtin_amdgcn_s_setprio(1);                                     \
            _Pragma("unroll")                                                  \
            for (int m = 0; m < 8; ++m)                                        \
                _Pragma("unroll")                                              \
                for (int n = 0; n < 4; ++n)                                    \
                    acc[m][n] = MFMA16(afr[m], bfr[n], acc[m][n]);             \
            __builtin_amdgcn_s_setprio(0);                                     \
            asm volatile("s_waitcnt vmcnt(0)" ::: "memory");                   \
            __builtin_amdgcn_s_barrier();                                      \
        } while (0)

    // prologue: tile 0 -> buf0
    STG(0, 0);
    asm volatile("s_waitcnt vmcnt(0)" ::: "memory");
    __builtin_amdgcn_s_barrier();

    for (int t = 0; t < NTT; t += 2) {
        TILE(0, t);
        TILE(1, t + 1);
    }

    // epilogue: C/D layout col=lane&15, row=(lane>>4)*4+reg (m89-verified)
    const int fq = lane >> 4;
    #pragma unroll
    for (int m = 0; m < 8; ++m)
        #pragma unroll
        for (int n = 0; n < 4; ++n)
            #pragma unroll
            for (int i = 0; i < 4; ++i) {
                int rr = row0 + m * 16 + fq * 4 + i;
                int cc = col0 + w * 64 + n * 16 + fr;
                Y[(size_t)rr * N_OUT + cc] = acc[m][n][i];
            }
    #undef TILE
    #undef STG
}

// ---------- slow correct fallback (only if ws too small) ----------
__global__ __launch_bounds__(256) void fallback_kernel(
    const float* __restrict__ xf, const int* __restrict__ q,
    const void* __restrict__ maskp, const float* __restrict__ scales,
    float* __restrict__ Y, const int* __restrict__ flagp) {
    const int msize = flagp[0];
    const int o = blockIdx.x * 256 + threadIdx.x;
    const int t = blockIdx.y;
    const unsigned char* mb = (const unsigned char*)maskp;
    const ushort* mh = (const ushort*)maskp;
    const unsigned int* mi = (const unsigned int*)maskp;
    float s = scales[o];
    float acc = 0.f;
    for (int i = 0; i < K_IN; ++i) {
        float x = bf2f(f2bf(xf[(size_t)t * K_IN + i]));
        size_t gi = (size_t)i * N_OUT + o;
        bool m;
        if (msize == 1)      m = (mb[gi] != 0);
        else if (msize == 2) m = (mh[gi] != 0);
        else                 m = (mi[gi] != 0);
        if (m) acc += x * bf2f(f2bf((float)(q[gi] - 8) * s));
    }
    Y[(size_t)t * N_OUT + o] = acc;
}

extern "C" void kernel_launch(void* const* d_in, const int* in_sizes, int n_in,
                              void* d_out, int out_size, void* d_ws, size_t ws_size,
                              hipStream_t stream) {
    const float* x      = (const float*)d_in[0];
    const int*   q      = (const int*)d_in[1];
    const void*  mask   = d_in[2];
    const float* scales = (const float*)d_in[3];
    float* y = (float*)d_out;

    const size_t BT_OFF = 64;
    const size_t XB_OFF = BT_OFF + (size_t)N_OUT * K_IN * 2;   // 64 + 32MB
    const size_t need   = XB_OFF + (size_t)M_TOK * K_IN * 2;   // + 64MB

    int* flags = (int*)d_ws;
    detect_kernel<<<1, 256, 0, stream>>>((const unsigned char*)mask, flags);

    if (ws_size >= need) {
        ushort* Bt = (ushort*)((char*)d_ws + BT_OFF);
        ushort* Xb = (ushort*)((char*)d_ws + XB_OFF);
        prep_kernel<<<8192, 256, 0, stream>>>(x, Xb, q, mask, scales, Bt, flags);
        gemm_kernel<<<dim3((M_TOK / 128) * (N_OUT / 256)), 256, 0, stream>>>(
            Xb, Bt, y);
    } else {
        fallback_kernel<<<dim3(N_OUT / 256, M_TOK), 256, 0, stream>>>(
            x, q, mask, scales, y, flags);
    }
}